// Round 4
// baseline (328.654 us; speedup 1.0000x reference)
//
#include <hip/hip_runtime.h>

// Problem constants: B=8, T=256, O=16, D=512, H=8, HD=64
// R = B*T*O = 32768 rows of D=512

typedef __attribute__((ext_vector_type(8))) short bf16x8;
typedef __attribute__((ext_vector_type(4))) float f32x4;

#define MFMA16(a, b, c) __builtin_amdgcn_mfma_f32_16x16x32_bf16((a), (b), (c), 0, 0, 0)

__device__ __forceinline__ unsigned short f2bf(float f) {
  unsigned int u = __builtin_bit_cast(unsigned int, f);
  u += 0x7fffu + ((u >> 16) & 1u);   // RNE
  return (unsigned short)(u >> 16);
}

__device__ __forceinline__ unsigned int cvt_pk_bf16(float lo, float hi) {
  unsigned int r;
  asm("v_cvt_pk_bf16_f32 %0, %1, %2" : "=v"(r) : "v"(lo), "v"(hi));
  return r;
}

__device__ __forceinline__ void gload_lds16(const void* g, void* lds) {
  __builtin_amdgcn_global_load_lds((__attribute__((address_space(1))) void*)g,
                                   (__attribute__((address_space(3))) void*)lds,
                                   16, 0, 0);
}

// ---------------- workspace layout (bytes) ----------------
#define WS_ATT  0ull            // 32768*512*2 = 33554432  (bf16 att, written by k_attn)
#define WS_WT   33554432ull     // 2048*512*2  = 2097152
#define WS_Q    35651584ull     // 33554432  (B,O,H,T,HD) bf16
#define WS_K    69206016ull     // 33554432
#define WS_V    102760448ull    // 33554432
#define WS_MASK 136314880ull    // 32768 uchar canonical mask

// ---------------- K0a: weights -> bf16 transposed via LDS tiles ----------------
// grid (8 dtile, 8 etile, 4 which), 256 threads. Wt[which*512+e][d] = W[d][e]
__global__ void k_prep_w(const float* __restrict__ Wq, const float* __restrict__ Wk,
                         const float* __restrict__ Wv, const float* __restrict__ Wo,
                         unsigned short* __restrict__ Wt) {
  __shared__ float tl[64][65];
  const float* src = blockIdx.z == 0 ? Wq : blockIdx.z == 1 ? Wk : blockIdx.z == 2 ? Wv : Wo;
  const int d0 = blockIdx.x * 64, e0 = blockIdx.y * 64;
  const int tid = threadIdx.x;
  {
    const int dr = tid >> 2, ec = (tid & 3) * 16;
    const float4* srow = (const float4*)(src + (size_t)(d0 + dr) * 512 + e0 + ec);
#pragma unroll
    for (int j = 0; j < 4; ++j) {
      float4 v = srow[j];
      tl[dr][ec + j * 4 + 0] = v.x;
      tl[dr][ec + j * 4 + 1] = v.y;
      tl[dr][ec + j * 4 + 2] = v.z;
      tl[dr][ec + j * 4 + 3] = v.w;
    }
  }
  __syncthreads();
  const int dd0 = (tid & 7) * 8;
#pragma unroll
  for (int i = 0; i < 2; ++i) {
    int e = i * 32 + (tid >> 3);
    bf16x8 ob;
#pragma unroll
    for (int j = 0; j < 8; ++j) ob[j] = (short)f2bf(tl[dd0 + j][e]);
    *(bf16x8*)(Wt + ((size_t)blockIdx.z * 512 + e0 + e) * 512 + d0 + dd0) = ob;
  }
}

// ---------------- K0b: canonicalize mask (detect int32 vs byte-packed bool) ----------------
__global__ void k_prep_mask(const void* __restrict__ mraw, unsigned char* __restrict__ mout) {
  const unsigned int* u = (const unsigned int*)mraw;
  int lane = threadIdx.x & 63;
  int packed = __any(u[lane] > 1u);
  int idx = blockIdx.x * 256 + threadIdx.x;
  unsigned char m;
  if (packed) m = ((const unsigned char*)mraw)[idx] ? 1 : 0;
  else        m = u[idx] ? 1 : 0;
  mout[idx] = m;
}

// ---------------- K1: QKV GEMM, 128x128 tile, 4 waves, fused fp32->bf16 A-staging ----
// flat grid 3072 = 256 Mtiles x (4 ntiles x 3 which), XCD-bijective swizzle.
// LDS: A[128][64] swz 16KB @0, B[128][64] swz 16KB @16384. Per-wave out 64x64 (wr=w>>1, wc=w&1).
__global__ __launch_bounds__(256) void k_qkv(
    const float* __restrict__ X, const unsigned short* __restrict__ Wt,
    const float* __restrict__ bq, const float* __restrict__ bk, const float* __restrict__ bv,
    unsigned short* __restrict__ Qb, unsigned short* __restrict__ Kb, unsigned short* __restrict__ Vb) {
  __shared__ char sm[32768];
  const int tid = threadIdx.x, l = tid & 63, w = tid >> 6;
  const int lane15 = l & 15, quad = l >> 4;
  const int flat = blockIdx.x;
  const int swz = (flat & 7) * 384 + (flat >> 3);   // 3072%8==0 -> bijective
  const int mtile = swz & 255, yb = swz >> 8;
  const int which = yb >> 2, ntile = yb & 3;
  const int rbase = mtile * 128;
  const unsigned short* wgp = Wt + ((size_t)which * 512 + ntile * 128) * 512;
  const int wr = w >> 1, wc = w & 1;
  const int srow = tid >> 3;            // 0..31
  const int c16 = (tid & 7) * 16;
  char* const abase = sm;
  char* const bbase = sm + 16384;
  f32x4 acc[4][4] = {};
  for (int ks = 0; ks < 8; ++ks) {
    __syncthreads();
    // B: 4 x gload_lds (pre-swizzled source -> linear dest)
#pragma unroll
    for (int i = 0; i < 4; ++i) {
      int row = i * 32 + srow;
      gload_lds16((const char*)wgp + (size_t)row * 1024 + ks * 128 + (c16 ^ ((row & 7) << 4)),
                  bbase + i * 4096 + w * 1024);
    }
    // A: reg-stage fp32 X -> cvt_pk bf16 -> swizzled ds_write_b128
#pragma unroll
    for (int i = 0; i < 4; ++i) {
      int row = i * 32 + srow;
      const float4* xs = (const float4*)(X + (size_t)(rbase + row) * 512 + ks * 64 + (tid & 7) * 8);
      float4 v0 = xs[0], v1 = xs[1];
      uint4 pk;
      pk.x = cvt_pk_bf16(v0.x, v0.y);
      pk.y = cvt_pk_bf16(v0.z, v0.w);
      pk.z = cvt_pk_bf16(v1.x, v1.y);
      pk.w = cvt_pk_bf16(v1.z, v1.w);
      *(uint4*)(abase + row * 128 + (c16 ^ ((row & 7) << 4))) = pk;
    }
    __syncthreads();
#pragma unroll
    for (int kc = 0; kc < 2; ++kc) {
      bf16x8 af[4], bfr[4];
#pragma unroll
      for (int mt = 0; mt < 4; ++mt) {
        int row = wr * 64 + mt * 16 + lane15;
        af[mt] = *(const bf16x8*)(abase + row * 128 + ((kc * 64 + quad * 16) ^ ((row & 7) << 4)));
      }
#pragma unroll
      for (int nt = 0; nt < 4; ++nt) {
        int col = wc * 64 + nt * 16 + lane15;
        bfr[nt] = *(const bf16x8*)(bbase + col * 128 + ((kc * 64 + quad * 16) ^ ((col & 7) << 4)));
      }
#pragma unroll
      for (int mt = 0; mt < 4; ++mt)
#pragma unroll
        for (int nt = 0; nt < 4; ++nt)
          acc[mt][nt] = MFMA16(af[mt], bfr[nt], acc[mt][nt]);
    }
  }
  const float* bias = (which == 0) ? bq : (which == 1) ? bk : bv;
  unsigned short* dst = (which == 0) ? Qb : (which == 1) ? Kb : Vb;
  const int h = ntile * 2 + wc;          // global col = h*64 + hd
#pragma unroll
  for (int mt = 0; mt < 4; ++mt) {
#pragma unroll
    for (int reg = 0; reg < 4; ++reg) {
      int r = rbase + wr * 64 + mt * 16 + quad * 4 + reg;
      int b = r >> 12, t = (r >> 4) & 255, o = r & 15;
      size_t base_bt = (size_t)((b * 16 + o) * 8 + h) * 16384 + (size_t)t * 64;
#pragma unroll
      for (int nt = 0; nt < 4; ++nt) {
        int hd = nt * 16 + lane15;
        dst[base_bt + hd] = f2bf(acc[mt][nt][reg] + bias[h * 64 + hd]);
      }
    }
  }
}

// ---------------- K2: attention per (b,o,h) — single-pass full-S (unchanged) ----------------
__global__ __launch_bounds__(512, 2) void k_attn(
    const unsigned short* __restrict__ Qb, const unsigned short* __restrict__ Kb,
    const unsigned short* __restrict__ Vb, const unsigned char* __restrict__ Mc,
    unsigned short* __restrict__ att) {
  __shared__ char sm[99328];
  const int tid = threadIdx.x, l = tid & 63, w = tid >> 6;
  const int lane15 = l & 15, quad = l >> 4;
  const int bid = blockIdx.x;
  const int h = bid & 7, o = (bid >> 3) & 15, b = bid >> 7;
  const size_t head = (size_t)((b * 16 + o) * 8 + h) * 16384;
  const unsigned short* qh = Qb + head;
  const char* kg = (const char*)(Kb + head);
  const unsigned short* vh = Vb + head;

  {
    const int srow = tid >> 3;
    const int c16 = (tid & 7) * 16;
    char* kdst = sm + w * 1024;
#pragma unroll
    for (int i = 0; i < 4; ++i) {
      int t = i * 64 + srow;
      gload_lds16(kg + (size_t)t * 128 + (c16 ^ ((t & 7) << 4)), kdst + i * 8192);
    }
  }
  const int q0 = w * 32;
  bf16x8 qf[2][2];
#pragma unroll
  for (int mt = 0; mt < 2; ++mt)
#pragma unroll
    for (int kc = 0; kc < 2; ++kc)
      qf[mt][kc] = *(const bf16x8*)(qh + (size_t)(q0 + mt * 16 + lane15) * 64 + kc * 32 + quad * 8);
  unsigned short vreg[32];
  {
    const int hd = tid & 63, tq = tid >> 6;
#pragma unroll
    for (int i = 0; i < 4; ++i)
#pragma unroll
      for (int j = 0; j < 8; ++j)
        vreg[i * 8 + j] = vh[(size_t)(tq * 32 + i * 8 + j) * 64 + hd];
  }
  float* maskb = (float*)(sm + 98304);
  if (tid < 256)
    maskb[tid] = Mc[(size_t)(b * 256 + tid) * 16 + o] ? 0.0f : -43280.0f;
  {
    const int hd = tid & 63, tq = tid >> 6;
    const int rowb = 32768 + hd * 512;
    const int swz = (hd & 7) << 4;
#pragma unroll
    for (int i = 0; i < 4; ++i) {
      bf16x8 pk;
#pragma unroll
      for (int j = 0; j < 8; ++j) pk[j] = (short)vreg[i * 8 + j];
      int t0 = tq * 32 + i * 8;
      *(bf16x8*)(sm + rowb + ((t0 * 2) ^ swz)) = pk;
    }
  }
  __syncthreads();

  f32x4 sacc[2][16] = {};
#pragma unroll
  for (int c = 0; c < 4; ++c) {
#pragma unroll
    for (int kc = 0; kc < 2; ++kc) {
      bf16x8 kf[4];
#pragma unroll
      for (int nt = 0; nt < 4; ++nt) {
        int t = c * 64 + nt * 16 + lane15;
        int byt = t * 128 + ((kc * 64 + quad * 16) ^ ((t & 7) << 4));
        kf[nt] = *(const bf16x8*)(sm + byt);
      }
#pragma unroll
      for (int mt = 0; mt < 2; ++mt)
#pragma unroll
        for (int nt = 0; nt < 4; ++nt)
          sacc[mt][c * 4 + nt] = MFMA16(qf[mt][kc], kf[nt], sacc[mt][c * 4 + nt]);
    }
  }

  float biasv[16];
#pragma unroll
  for (int g = 0; g < 16; ++g) biasv[g] = maskb[g * 16 + lane15];
  float inv[2][4];
#pragma unroll
  for (int mt = 0; mt < 2; ++mt) {
#pragma unroll
    for (int reg = 0; reg < 4; ++reg) {
      float v[16];
#pragma unroll
      for (int g = 0; g < 16; ++g)
        v[g] = sacc[mt][g][reg] * 0.18033688f + biasv[g];
      float m = v[0];
#pragma unroll
      for (int g = 1; g < 16; ++g) m = fmaxf(m, v[g]);
#pragma unroll
      for (int d = 1; d < 16; d <<= 1) m = fmaxf(m, __shfl_xor(m, d));
      float rs = 0.f;
#pragma unroll
      for (int g = 0; g < 16; ++g) {
        float p = __builtin_amdgcn_exp2f(v[g] - m);
        sacc[mt][g][reg] = p;
        rs += p;
      }
#pragma unroll
      for (int d = 1; d < 16; d <<= 1) rs += __shfl_xor(rs, d);
      inv[mt][reg] = 1.0f / rs;
    }
  }

  char* pb = sm + 65536 + w * 4096;
  f32x4 pv[2][4] = {};
#pragma unroll
  for (int c = 0; c < 4; ++c) {
#pragma unroll
    for (int mt = 0; mt < 2; ++mt)
#pragma unroll
      for (int nt = 0; nt < 4; ++nt)
#pragma unroll
        for (int reg = 0; reg < 4; ++reg) {
          int qrow = mt * 16 + quad * 4 + reg;
          int byt = (qrow * 128 + (nt * 16 + lane15) * 2) ^ ((qrow & 7) << 4);
          *(unsigned short*)(pb + byt) = f2bf(sacc[mt][c * 4 + nt][reg]);
        }
#pragma unroll
    for (int kc = 0; kc < 2; ++kc) {
      bf16x8 pa[2], vbr[4];
#pragma unroll
      for (int mt = 0; mt < 2; ++mt) {
        int qrow = mt * 16 + lane15;
        int byt = (qrow * 128 + kc * 64 + quad * 16) ^ ((qrow & 7) << 4);
        pa[mt] = *(const bf16x8*)(pb + byt);
      }
#pragma unroll
      for (int nh = 0; nh < 4; ++nh) {
        int hd = nh * 16 + lane15;
        int byt = hd * 512 + ((c * 128 + kc * 64 + quad * 16) ^ ((hd & 7) << 4));
        vbr[nh] = *(const bf16x8*)(sm + 32768 + byt);
      }
#pragma unroll
      for (int mt = 0; mt < 2; ++mt)
#pragma unroll
        for (int nh = 0; nh < 4; ++nh)
          pv[mt][nh] = MFMA16(pa[mt], vbr[nh], pv[mt][nh]);
    }
  }

#pragma unroll
  for (int mt = 0; mt < 2; ++mt) {
#pragma unroll
    for (int reg = 0; reg < 4; ++reg) {
      int q = q0 + mt * 16 + quad * 4 + reg;
      size_t r = (size_t)(b * 256 + q) * 16 + o;
      float iv = inv[mt][reg];
#pragma unroll
      for (int nh = 0; nh < 4; ++nh)
        att[r * 512 + h * 64 + nh * 16 + lane15] = f2bf(pv[mt][nh][reg] * iv);
    }
  }
}

// ---------------- K3: O-proj + bias + residual + LayerNorm + mask (unchanged) -------------
__global__ __launch_bounds__(512) void k_oproj(
    const unsigned short* __restrict__ A, const unsigned short* __restrict__ Wt,
    const float* __restrict__ bo, const float* __restrict__ X,
    const unsigned char* __restrict__ Mc, const float* __restrict__ gamma,
    const float* __restrict__ beta, float* __restrict__ out) {
  __shared__ char sm[73728];
  __shared__ float psum[64][8];
  __shared__ float psumsq[64][8];
  __shared__ float smean[64];
  __shared__ float srstd[64];
  const int tid = threadIdx.x, l = tid & 63, w = tid >> 6;
  const int lane15 = l & 15, quad = l >> 4;
  const int rbase = blockIdx.x * 64;
  const char* ag = (const char*)A;
  const char* wgp = (const char*)(Wt + (size_t)1536 * 512);
  const int srow = tid >> 3;
  const int c16 = (tid & 7) * 16;
  const int swz_a = c16 ^ ((srow & 7) << 4);
  char* adst = sm + w * 1024;
  f32x4 acc[4][4] = {};
  for (int ks = 0; ks < 8; ++ks) {
    __syncthreads();
    gload_lds16(ag + (size_t)(rbase + srow) * 1024 + ks * 128 + swz_a, adst);
#pragma unroll
    for (int p = 0; p < 8; ++p) {
      int er = p * 64 + srow;
      gload_lds16(wgp + (size_t)er * 1024 + ks * 128 + (c16 ^ ((er & 7) << 4)),
                  sm + 8192 + p * 8192 + w * 1024);
    }
    __syncthreads();
#pragma unroll
    for (int kc = 0; kc < 2; ++kc) {
      bf16x8 af[4], bfr[4];
#pragma unroll
      for (int mt = 0; mt < 4; ++mt) {
        int row = mt * 16 + lane15;
        int byt = (row * 128 + kc * 64 + quad * 16) ^ ((row & 7) << 4);
        af[mt] = *(const bf16x8*)(sm + byt);
      }
#pragma unroll
      for (int nt = 0; nt < 4; ++nt) {
        int col = w * 64 + nt * 16 + lane15;
        int byt = (col * 128 + kc * 64 + quad * 16) ^ ((col & 7) << 4);
        bfr[nt] = *(const bf16x8*)(sm + 8192 + byt);
      }
#pragma unroll
      for (int mt = 0; mt < 4; ++mt)
#pragma unroll
        for (int nt = 0; nt < 4; ++nt)
          acc[mt][nt] = MFMA16(af[mt], bfr[nt], acc[mt][nt]);
    }
  }
#pragma unroll
  for (int mt = 0; mt < 4; ++mt) {
#pragma unroll
    for (int reg = 0; reg < 4; ++reg) {
      int rl = mt * 16 + quad * 4 + reg;
      int r = rbase + rl;
      float s1 = 0.f, s2 = 0.f;
#pragma unroll
      for (int nt = 0; nt < 4; ++nt) {
        int col = w * 64 + nt * 16 + lane15;
        float v = acc[mt][nt][reg] + bo[col] + X[(size_t)r * 512 + col];
        acc[mt][nt][reg] = v;
        s1 += v; s2 += v * v;
      }
#pragma unroll
      for (int d = 1; d < 16; d <<= 1) { s1 += __shfl_xor(s1, d); s2 += __shfl_xor(s2, d); }
      if (lane15 == 0) { psum[rl][w] = s1; psumsq[rl][w] = s2; }
    }
  }
  __syncthreads();
  if (tid < 64) {
    float a = 0.f, q = 0.f;
#pragma unroll
    for (int j = 0; j < 8; ++j) { a += psum[tid][j]; q += psumsq[tid][j]; }
    float mu = a * (1.f / 512.f);
    float var = q * (1.f / 512.f) - mu * mu;
    smean[tid] = mu;
    srstd[tid] = rsqrtf(fmaxf(var, 0.f) + 1e-5f);
  }
  __syncthreads();
#pragma unroll
  for (int mt = 0; mt < 4; ++mt) {
#pragma unroll
    for (int reg = 0; reg < 4; ++reg) {
      int rl = mt * 16 + quad * 4 + reg;
      int r = rbase + rl;
      float mu = smean[rl], rs = srstd[rl];
      float mkf = Mc[r] ? 1.f : 0.f;
#pragma unroll
      for (int nt = 0; nt < 4; ++nt) {
        int col = w * 64 + nt * 16 + lane15;
        float y = (acc[mt][nt][reg] - mu) * rs * gamma[col] + beta[col];
        out[(size_t)r * 512 + col] = y * mkf;
      }
    }
  }
}

// ---------------- host ----------------
extern "C" void kernel_launch(void* const* d_in, const int* in_sizes, int n_in,
                              void* d_out, int out_size, void* d_ws, size_t ws_size,
                              hipStream_t stream) {
  const float* X     = (const float*)d_in[0];
  const void*  Mraw  = d_in[1];
  const float* Wq    = (const float*)d_in[2];
  const float* bq    = (const float*)d_in[3];
  const float* Wk    = (const float*)d_in[4];
  const float* bk    = (const float*)d_in[5];
  const float* Wv    = (const float*)d_in[6];
  const float* bv    = (const float*)d_in[7];
  const float* Wo    = (const float*)d_in[8];
  const float* bo    = (const float*)d_in[9];
  const float* gamma = (const float*)d_in[10];
  const float* beta  = (const float*)d_in[11];

  char* ws = (char*)d_ws;
  unsigned short* att = (unsigned short*)(ws + WS_ATT);
  unsigned short* Wt  = (unsigned short*)(ws + WS_WT);
  unsigned short* Qb  = (unsigned short*)(ws + WS_Q);
  unsigned short* Kb  = (unsigned short*)(ws + WS_K);
  unsigned short* Vb  = (unsigned short*)(ws + WS_V);
  unsigned char*  Mc  = (unsigned char*)(ws + WS_MASK);

  hipLaunchKernelGGL(k_prep_w,   dim3(8, 8, 4), dim3(256), 0, stream, Wq, Wk, Wv, Wo, Wt);
  hipLaunchKernelGGL(k_prep_mask,dim3(128),     dim3(256), 0, stream, Mraw, Mc);
  hipLaunchKernelGGL(k_qkv,      dim3(3072),    dim3(256), 0, stream, X, Wt, bq, bk, bv, Qb, Kb, Vb);
  hipLaunchKernelGGL(k_attn,     dim3(1024),    dim3(512), 0, stream, Qb, Kb, Vb, Mc, att);
  hipLaunchKernelGGL(k_oproj,    dim3(512),     dim3(512), 0, stream, att, Wt, bo, X, Mc, gamma, beta,
                     (float*)d_out);
}

// Round 5
// 297.526 us; speedup vs baseline: 1.1046x; 1.1046x over previous
//
#include <hip/hip_runtime.h>

// Problem constants: B=8, T=256, O=16, D=512, H=8, HD=64
// R = B*T*O = 32768 rows of D=512

typedef __attribute__((ext_vector_type(8))) short bf16x8;
typedef __attribute__((ext_vector_type(4))) float f32x4;

#define MFMA16(a, b, c) __builtin_amdgcn_mfma_f32_16x16x32_bf16((a), (b), (c), 0, 0, 0)

__device__ __forceinline__ unsigned short f2bf(float f) {
  unsigned int u = __builtin_bit_cast(unsigned int, f);
  u += 0x7fffu + ((u >> 16) & 1u);   // RNE
  return (unsigned short)(u >> 16);
}

__device__ __forceinline__ void gload_lds16(const void* g, void* lds) {
  __builtin_amdgcn_global_load_lds((__attribute__((address_space(1))) void*)g,
                                   (__attribute__((address_space(3))) void*)lds,
                                   16, 0, 0);
}

// ---------------- workspace layout (bytes) ----------------
#define WS_XB   0ull            // 32768*512*2 = 33554432  (bf16 X; reused as att after qkv)
#define WS_WT   33554432ull     // 2048*512*2  = 2097152
#define WS_Q    35651584ull     // 33554432  (B,O,H,T,HD) bf16
#define WS_K    69206016ull     // 33554432
#define WS_V    102760448ull    // 33554432
#define WS_MASK 136314880ull    // 32768 uchar canonical mask

// ---------------- K0a: X fp32 -> bf16 ----------------
__global__ void k_cvt_x(const float* __restrict__ x, unsigned short* __restrict__ xb) {
  int i = blockIdx.x * 256 + threadIdx.x;   // 16384 blocks -> exactly 4194304 float4
  float4 v = ((const float4*)x)[i];
  ushort4 o;
  o.x = f2bf(v.x); o.y = f2bf(v.y); o.z = f2bf(v.z); o.w = f2bf(v.w);
  ((ushort4*)xb)[i] = o;
}

// ---------------- K0b: weights -> bf16 transposed via LDS tiles ----------------
// grid (8 dtile, 8 etile, 4 which), 256 threads. Wt[which*512+e][d] = W[d][e]
__global__ void k_prep_w(const float* __restrict__ Wq, const float* __restrict__ Wk,
                         const float* __restrict__ Wv, const float* __restrict__ Wo,
                         unsigned short* __restrict__ Wt) {
  __shared__ float tl[64][65];
  const float* src = blockIdx.z == 0 ? Wq : blockIdx.z == 1 ? Wk : blockIdx.z == 2 ? Wv : Wo;
  const int d0 = blockIdx.x * 64, e0 = blockIdx.y * 64;
  const int tid = threadIdx.x;
  {
    const int dr = tid >> 2, ec = (tid & 3) * 16;
    const float4* srow = (const float4*)(src + (size_t)(d0 + dr) * 512 + e0 + ec);
#pragma unroll
    for (int j = 0; j < 4; ++j) {
      float4 v = srow[j];
      tl[dr][ec + j * 4 + 0] = v.x;
      tl[dr][ec + j * 4 + 1] = v.y;
      tl[dr][ec + j * 4 + 2] = v.z;
      tl[dr][ec + j * 4 + 3] = v.w;
    }
  }
  __syncthreads();
  const int dd0 = (tid & 7) * 8;
#pragma unroll
  for (int i = 0; i < 2; ++i) {
    int e = i * 32 + (tid >> 3);
    bf16x8 ob;
#pragma unroll
    for (int j = 0; j < 8; ++j) ob[j] = (short)f2bf(tl[dd0 + j][e]);
    *(bf16x8*)(Wt + ((size_t)blockIdx.z * 512 + e0 + e) * 512 + d0 + dd0) = ob;
  }
}

// ---------------- K0c: canonicalize mask (detect int32 vs byte-packed bool) ----------------
__global__ void k_prep_mask(const void* __restrict__ mraw, unsigned char* __restrict__ mout) {
  const unsigned int* u = (const unsigned int*)mraw;
  int lane = threadIdx.x & 63;
  int packed = __any(u[lane] > 1u);
  int idx = blockIdx.x * 256 + threadIdx.x;
  unsigned char m;
  if (packed) m = ((const unsigned char*)mraw)[idx] ? 1 : 0;
  else        m = u[idx] ? 1 : 0;
  mout[idx] = m;
}

// ---------------- K1: QKV GEMM, 128x128 tile, 4 waves, A and B via global_load_lds ----
// flat grid 3072 = mtile*12 + (which*4 + ntile); natural order keeps the 12 N-variants
// of one mtile dispatch-adjacent -> X rows L3-hot. LDS: A[128][64]swz 16KB @0,
// B[128][64]swz 16KB @16384. Per-wave out 64x64 (wr=w>>1, wc=w&1).
__global__ __launch_bounds__(256) void k_qkv(
    const unsigned short* __restrict__ Xb, const unsigned short* __restrict__ Wt,
    const float* __restrict__ bq, const float* __restrict__ bk, const float* __restrict__ bv,
    unsigned short* __restrict__ Qb, unsigned short* __restrict__ Kb, unsigned short* __restrict__ Vb) {
  __shared__ char sm[32768];
  const int tid = threadIdx.x, l = tid & 63, w = tid >> 6;
  const int lane15 = l & 15, quad = l >> 4;
  const int flat = blockIdx.x;
  const int mtile = flat / 12, yb = flat % 12;
  const int which = yb >> 2, ntile = yb & 3;
  const int rbase = mtile * 128;
  const char* xg = (const char*)Xb + (size_t)rbase * 1024;
  const char* wgp = (const char*)(Wt + ((size_t)which * 512 + ntile * 128) * 512);
  const int wr = w >> 1, wc = w & 1;
  const int srow = tid >> 3;            // 0..31
  const int c16 = (tid & 7) * 16;
  char* const abase = sm;
  char* const bbase = sm + 16384;
  f32x4 acc[4][4] = {};
  for (int ks = 0; ks < 8; ++ks) {
    __syncthreads();
#pragma unroll
    for (int i = 0; i < 4; ++i) {
      int row = i * 32 + srow;
      int swz = c16 ^ ((row & 7) << 4);
      gload_lds16(xg + (size_t)row * 1024 + ks * 128 + swz, abase + i * 4096 + w * 1024);
      gload_lds16(wgp + (size_t)row * 1024 + ks * 128 + swz, bbase + i * 4096 + w * 1024);
    }
    __syncthreads();
#pragma unroll
    for (int kc = 0; kc < 2; ++kc) {
      bf16x8 af[4], bfr[4];
#pragma unroll
      for (int mt = 0; mt < 4; ++mt) {
        int row = wr * 64 + mt * 16 + lane15;
        af[mt] = *(const bf16x8*)(abase + row * 128 + ((kc * 64 + quad * 16) ^ ((row & 7) << 4)));
      }
#pragma unroll
      for (int nt = 0; nt < 4; ++nt) {
        int col = wc * 64 + nt * 16 + lane15;
        bfr[nt] = *(const bf16x8*)(bbase + col * 128 + ((kc * 64 + quad * 16) ^ ((col & 7) << 4)));
      }
#pragma unroll
      for (int mt = 0; mt < 4; ++mt)
#pragma unroll
        for (int nt = 0; nt < 4; ++nt)
          acc[mt][nt] = MFMA16(af[mt], bfr[nt], acc[mt][nt]);
    }
  }
  const float* bias = (which == 0) ? bq : (which == 1) ? bk : bv;
  unsigned short* dst = (which == 0) ? Qb : (which == 1) ? Kb : Vb;
  const int h = ntile * 2 + wc;          // global col = h*64 + hd
#pragma unroll
  for (int mt = 0; mt < 4; ++mt) {
#pragma unroll
    for (int reg = 0; reg < 4; ++reg) {
      int r = rbase + wr * 64 + mt * 16 + quad * 4 + reg;
      int b = r >> 12, t = (r >> 4) & 255, o = r & 15;
      size_t base_bt = (size_t)((b * 16 + o) * 8 + h) * 16384 + (size_t)t * 64;
#pragma unroll
      for (int nt = 0; nt < 4; ++nt) {
        int hd = nt * 16 + lane15;
        dst[base_bt + hd] = f2bf(acc[mt][nt][reg] + bias[h * 64 + hd]);
      }
    }
  }
}

// ---------------- K2: attention per (b,o,h) — single-pass full-S (unchanged) ----------------
__global__ __launch_bounds__(512, 2) void k_attn(
    const unsigned short* __restrict__ Qb, const unsigned short* __restrict__ Kb,
    const unsigned short* __restrict__ Vb, const unsigned char* __restrict__ Mc,
    unsigned short* __restrict__ att) {
  __shared__ char sm[99328];
  const int tid = threadIdx.x, l = tid & 63, w = tid >> 6;
  const int lane15 = l & 15, quad = l >> 4;
  const int bid = blockIdx.x;
  const int h = bid & 7, o = (bid >> 3) & 15, b = bid >> 7;
  const size_t head = (size_t)((b * 16 + o) * 8 + h) * 16384;
  const unsigned short* qh = Qb + head;
  const char* kg = (const char*)(Kb + head);
  const unsigned short* vh = Vb + head;

  {
    const int srow = tid >> 3;
    const int c16 = (tid & 7) * 16;
    char* kdst = sm + w * 1024;
#pragma unroll
    for (int i = 0; i < 4; ++i) {
      int t = i * 64 + srow;
      gload_lds16(kg + (size_t)t * 128 + (c16 ^ ((t & 7) << 4)), kdst + i * 8192);
    }
  }
  const int q0 = w * 32;
  bf16x8 qf[2][2];
#pragma unroll
  for (int mt = 0; mt < 2; ++mt)
#pragma unroll
    for (int kc = 0; kc < 2; ++kc)
      qf[mt][kc] = *(const bf16x8*)(qh + (size_t)(q0 + mt * 16 + lane15) * 64 + kc * 32 + quad * 8);
  unsigned short vreg[32];
  {
    const int hd = tid & 63, tq = tid >> 6;
#pragma unroll
    for (int i = 0; i < 4; ++i)
#pragma unroll
      for (int j = 0; j < 8; ++j)
        vreg[i * 8 + j] = vh[(size_t)(tq * 32 + i * 8 + j) * 64 + hd];
  }
  float* maskb = (float*)(sm + 98304);
  if (tid < 256)
    maskb[tid] = Mc[(size_t)(b * 256 + tid) * 16 + o] ? 0.0f : -43280.0f;
  {
    const int hd = tid & 63, tq = tid >> 6;
    const int rowb = 32768 + hd * 512;
    const int swz = (hd & 7) << 4;
#pragma unroll
    for (int i = 0; i < 4; ++i) {
      bf16x8 pk;
#pragma unroll
      for (int j = 0; j < 8; ++j) pk[j] = (short)vreg[i * 8 + j];
      int t0 = tq * 32 + i * 8;
      *(bf16x8*)(sm + rowb + ((t0 * 2) ^ swz)) = pk;
    }
  }
  __syncthreads();

  f32x4 sacc[2][16] = {};
#pragma unroll
  for (int c = 0; c < 4; ++c) {
#pragma unroll
    for (int kc = 0; kc < 2; ++kc) {
      bf16x8 kf[4];
#pragma unroll
      for (int nt = 0; nt < 4; ++nt) {
        int t = c * 64 + nt * 16 + lane15;
        int byt = t * 128 + ((kc * 64 + quad * 16) ^ ((t & 7) << 4));
        kf[nt] = *(const bf16x8*)(sm + byt);
      }
#pragma unroll
      for (int mt = 0; mt < 2; ++mt)
#pragma unroll
        for (int nt = 0; nt < 4; ++nt)
          sacc[mt][c * 4 + nt] = MFMA16(qf[mt][kc], kf[nt], sacc[mt][c * 4 + nt]);
    }
  }

  float biasv[16];
#pragma unroll
  for (int g = 0; g < 16; ++g) biasv[g] = maskb[g * 16 + lane15];
  float inv[2][4];
#pragma unroll
  for (int mt = 0; mt < 2; ++mt) {
#pragma unroll
    for (int reg = 0; reg < 4; ++reg) {
      float v[16];
#pragma unroll
      for (int g = 0; g < 16; ++g)
        v[g] = sacc[mt][g][reg] * 0.18033688f + biasv[g];
      float m = v[0];
#pragma unroll
      for (int g = 1; g < 16; ++g) m = fmaxf(m, v[g]);
#pragma unroll
      for (int d = 1; d < 16; d <<= 1) m = fmaxf(m, __shfl_xor(m, d));
      float rs = 0.f;
#pragma unroll
      for (int g = 0; g < 16; ++g) {
        float p = __builtin_amdgcn_exp2f(v[g] - m);
        sacc[mt][g][reg] = p;
        rs += p;
      }
#pragma unroll
      for (int d = 1; d < 16; d <<= 1) rs += __shfl_xor(rs, d);
      inv[mt][reg] = 1.0f / rs;
    }
  }

  char* pb = sm + 65536 + w * 4096;
  f32x4 pv[2][4] = {};
#pragma unroll
  for (int c = 0; c < 4; ++c) {
#pragma unroll
    for (int mt = 0; mt < 2; ++mt)
#pragma unroll
      for (int nt = 0; nt < 4; ++nt)
#pragma unroll
        for (int reg = 0; reg < 4; ++reg) {
          int qrow = mt * 16 + quad * 4 + reg;
          int byt = (qrow * 128 + (nt * 16 + lane15) * 2) ^ ((qrow & 7) << 4);
          *(unsigned short*)(pb + byt) = f2bf(sacc[mt][c * 4 + nt][reg]);
        }
#pragma unroll
    for (int kc = 0; kc < 2; ++kc) {
      bf16x8 pa[2], vbr[4];
#pragma unroll
      for (int mt = 0; mt < 2; ++mt) {
        int qrow = mt * 16 + lane15;
        int byt = (qrow * 128 + kc * 64 + quad * 16) ^ ((qrow & 7) << 4);
        pa[mt] = *(const bf16x8*)(pb + byt);
      }
#pragma unroll
      for (int nh = 0; nh < 4; ++nh) {
        int hd = nh * 16 + lane15;
        int byt = hd * 512 + ((c * 128 + kc * 64 + quad * 16) ^ ((hd & 7) << 4));
        vbr[nh] = *(const bf16x8*)(sm + 32768 + byt);
      }
#pragma unroll
      for (int mt = 0; mt < 2; ++mt)
#pragma unroll
        for (int nh = 0; nh < 4; ++nh)
          pv[mt][nh] = MFMA16(pa[mt], vbr[nh], pv[mt][nh]);
    }
  }

#pragma unroll
  for (int mt = 0; mt < 2; ++mt) {
#pragma unroll
    for (int reg = 0; reg < 4; ++reg) {
      int q = q0 + mt * 16 + quad * 4 + reg;
      size_t r = (size_t)(b * 256 + q) * 16 + o;
      float iv = inv[mt][reg];
#pragma unroll
      for (int nh = 0; nh < 4; ++nh)
        att[r * 512 + h * 64 + nh * 16 + lane15] = f2bf(pv[mt][nh][reg] * iv);
    }
  }
}

// ---------------- K3: O-proj + bias + residual + LayerNorm + mask (unchanged) -------------
__global__ __launch_bounds__(512) void k_oproj(
    const unsigned short* __restrict__ A, const unsigned short* __restrict__ Wt,
    const float* __restrict__ bo, const float* __restrict__ X,
    const unsigned char* __restrict__ Mc, const float* __restrict__ gamma,
    const float* __restrict__ beta, float* __restrict__ out) {
  __shared__ char sm[73728];
  __shared__ float psum[64][8];
  __shared__ float psumsq[64][8];
  __shared__ float smean[64];
  __shared__ float srstd[64];
  const int tid = threadIdx.x, l = tid & 63, w = tid >> 6;
  const int lane15 = l & 15, quad = l >> 4;
  const int rbase = blockIdx.x * 64;
  const char* ag = (const char*)A;
  const char* wgp = (const char*)(Wt + (size_t)1536 * 512);
  const int srow = tid >> 3;
  const int c16 = (tid & 7) * 16;
  const int swz_a = c16 ^ ((srow & 7) << 4);
  char* adst = sm + w * 1024;
  f32x4 acc[4][4] = {};
  for (int ks = 0; ks < 8; ++ks) {
    __syncthreads();
    gload_lds16(ag + (size_t)(rbase + srow) * 1024 + ks * 128 + swz_a, adst);
#pragma unroll
    for (int p = 0; p < 8; ++p) {
      int er = p * 64 + srow;
      gload_lds16(wgp + (size_t)er * 1024 + ks * 128 + (c16 ^ ((er & 7) << 4)),
                  sm + 8192 + p * 8192 + w * 1024);
    }
    __syncthreads();
#pragma unroll
    for (int kc = 0; kc < 2; ++kc) {
      bf16x8 af[4], bfr[4];
#pragma unroll
      for (int mt = 0; mt < 4; ++mt) {
        int row = mt * 16 + lane15;
        int byt = (row * 128 + kc * 64 + quad * 16) ^ ((row & 7) << 4);
        af[mt] = *(const bf16x8*)(sm + byt);
      }
#pragma unroll
      for (int nt = 0; nt < 4; ++nt) {
        int col = w * 64 + nt * 16 + lane15;
        int byt = (col * 128 + kc * 64 + quad * 16) ^ ((col & 7) << 4);
        bfr[nt] = *(const bf16x8*)(sm + 8192 + byt);
      }
#pragma unroll
      for (int mt = 0; mt < 4; ++mt)
#pragma unroll
        for (int nt = 0; nt < 4; ++nt)
          acc[mt][nt] = MFMA16(af[mt], bfr[nt], acc[mt][nt]);
    }
  }
#pragma unroll
  for (int mt = 0; mt < 4; ++mt) {
#pragma unroll
    for (int reg = 0; reg < 4; ++reg) {
      int rl = mt * 16 + quad * 4 + reg;
      int r = rbase + rl;
      float s1 = 0.f, s2 = 0.f;
#pragma unroll
      for (int nt = 0; nt < 4; ++nt) {
        int col = w * 64 + nt * 16 + lane15;
        float v = acc[mt][nt][reg] + bo[col] + X[(size_t)r * 512 + col];
        acc[mt][nt][reg] = v;
        s1 += v; s2 += v * v;
      }
#pragma unroll
      for (int d = 1; d < 16; d <<= 1) { s1 += __shfl_xor(s1, d); s2 += __shfl_xor(s2, d); }
      if (lane15 == 0) { psum[rl][w] = s1; psumsq[rl][w] = s2; }
    }
  }
  __syncthreads();
  if (tid < 64) {
    float a = 0.f, q = 0.f;
#pragma unroll
    for (int j = 0; j < 8; ++j) { a += psum[tid][j]; q += psumsq[tid][j]; }
    float mu = a * (1.f / 512.f);
    float var = q * (1.f / 512.f) - mu * mu;
    smean[tid] = mu;
    srstd[tid] = rsqrtf(fmaxf(var, 0.f) + 1e-5f);
  }
  __syncthreads();
#pragma unroll
  for (int mt = 0; mt < 4; ++mt) {
#pragma unroll
    for (int reg = 0; reg < 4; ++reg) {
      int rl = mt * 16 + quad * 4 + reg;
      int r = rbase + rl;
      float mu = smean[rl], rs = srstd[rl];
      float mkf = Mc[r] ? 1.f : 0.f;
#pragma unroll
      for (int nt = 0; nt < 4; ++nt) {
        int col = w * 64 + nt * 16 + lane15;
        float y = (acc[mt][nt][reg] - mu) * rs * gamma[col] + beta[col];
        out[(size_t)r * 512 + col] = y * mkf;
      }
    }
  }
}

// ---------------- host ----------------
extern "C" void kernel_launch(void* const* d_in, const int* in_sizes, int n_in,
                              void* d_out, int out_size, void* d_ws, size_t ws_size,
                              hipStream_t stream) {
  const float* X     = (const float*)d_in[0];
  const void*  Mraw  = d_in[1];
  const float* Wq    = (const float*)d_in[2];
  const float* bq    = (const float*)d_in[3];
  const float* Wk    = (const float*)d_in[4];
  const float* bk    = (const float*)d_in[5];
  const float* Wv    = (const float*)d_in[6];
  const float* bv    = (const float*)d_in[7];
  const float* Wo    = (const float*)d_in[8];
  const float* bo    = (const float*)d_in[9];
  const float* gamma = (const float*)d_in[10];
  const float* beta  = (const float*)d_in[11];

  char* ws = (char*)d_ws;
  unsigned short* Xb  = (unsigned short*)(ws + WS_XB);
  unsigned short* Wt  = (unsigned short*)(ws + WS_WT);
  unsigned short* Qb  = (unsigned short*)(ws + WS_Q);
  unsigned short* Kb  = (unsigned short*)(ws + WS_K);
  unsigned short* Vb  = (unsigned short*)(ws + WS_V);
  unsigned char*  Mc  = (unsigned char*)(ws + WS_MASK);
  unsigned short* att = Xb;  // alias: Xb dead after k_qkv

  hipLaunchKernelGGL(k_cvt_x,    dim3(16384),   dim3(256), 0, stream, X, Xb);
  hipLaunchKernelGGL(k_prep_w,   dim3(8, 8, 4), dim3(256), 0, stream, Wq, Wk, Wv, Wo, Wt);
  hipLaunchKernelGGL(k_prep_mask,dim3(128),     dim3(256), 0, stream, Mraw, Mc);
  hipLaunchKernelGGL(k_qkv,      dim3(3072),    dim3(256), 0, stream, Xb, Wt, bq, bk, bv, Qb, Kb, Vb);
  hipLaunchKernelGGL(k_attn,     dim3(1024),    dim3(512), 0, stream, Qb, Kb, Vb, Mc, att);
  hipLaunchKernelGGL(k_oproj,    dim3(512),     dim3(512), 0, stream, att, Wt, bo, X, Mc, gamma, beta,
                     (float*)d_out);
}